// Round 1
// baseline (483.693 us; speedup 1.0000x reference)
//
#include <hip/hip_runtime.h>

#define B_ 4
#define S_ 2048
#define E_ 768
#define H_ 12
#define D_ 64
#define IMG_ 196
#define TXT_ 1852
#define NEG_ (-1e9f)

typedef __bf16 bf16x8 __attribute__((ext_vector_type(8)));
typedef float f32x4 __attribute__((ext_vector_type(4)));

__device__ __forceinline__ unsigned short f2b(float f) {
    __bf16 h = (__bf16)f;
    return __builtin_bit_cast(unsigned short, h);
}

// ---------------------------------------------------------------- conversion
__global__ __launch_bounds__(256) void cvt_kernel(const float* __restrict__ src,
                                                  unsigned short* __restrict__ dst,
                                                  int n4) {
    int i = blockIdx.x * 256 + threadIdx.x;
    if (i < n4) {
        float4 f = reinterpret_cast<const float4*>(src)[i];
        ushort4 u;
        u.x = f2b(f.x); u.y = f2b(f.y); u.z = f2b(f.z); u.w = f2b(f.w);
        reinterpret_cast<ushort4*>(dst)[i] = u;
    }
}

// ---------------------------------------------------------------- QKV GEMM
// Y[i][o] = sum_e X[i][e] * W[o][e] + b[o], X:[8192][768], W:[768][768] x3
// 128x128 tile, BK=32, 4 waves each 64x64 (4x4 frags of 16x16x32)
__global__ __launch_bounds__(256) void qkv_gemm(
    const unsigned short* __restrict__ xb,
    const unsigned short* __restrict__ wqb,
    const unsigned short* __restrict__ wkb,
    const unsigned short* __restrict__ wvb,
    const float* __restrict__ bq, const float* __restrict__ bk,
    const float* __restrict__ bv,
    unsigned short* __restrict__ qb, unsigned short* __restrict__ kb,
    unsigned short* __restrict__ vtb)
{
    __shared__ __align__(16) unsigned short As[128][40];
    __shared__ __align__(16) unsigned short Bs[128][40];
    const int m0 = blockIdx.x * 128;
    const int n0 = blockIdx.y * 128;
    const int which = n0 / E_;           // 0=q 1=k 2=v (tile never straddles)
    const int ncol0 = n0 % E_;
    const unsigned short* W = (which == 0) ? wqb : ((which == 1) ? wkb : wvb);
    const int t = threadIdx.x;
    const int lane = t & 63, wid = t >> 6;
    const int wr = wid >> 1, wc = wid & 1;
    const int c = lane & 15, g = lane >> 4;

    f32x4 acc[4][4];
#pragma unroll
    for (int i = 0; i < 4; ++i)
#pragma unroll
        for (int j = 0; j < 4; ++j) acc[i][j] = (f32x4){0.f, 0.f, 0.f, 0.f};

    for (int k0 = 0; k0 < E_; k0 += 32) {
        __syncthreads();
#pragma unroll
        for (int p = 0; p < 2; ++p) {
            int idx = t + p * 256;
            int row = idx >> 2, ch = idx & 3;
            *reinterpret_cast<uint4*>(&As[row][ch * 8]) =
                *reinterpret_cast<const uint4*>(xb + (size_t)(m0 + row) * E_ + k0 + ch * 8);
            *reinterpret_cast<uint4*>(&Bs[row][ch * 8]) =
                *reinterpret_cast<const uint4*>(W + (size_t)(ncol0 + row) * E_ + k0 + ch * 8);
        }
        __syncthreads();
        bf16x8 af[4], bfv[4];
#pragma unroll
        for (int fr = 0; fr < 4; ++fr)
            af[fr] = *reinterpret_cast<const bf16x8*>(&As[wr * 64 + fr * 16 + c][g * 8]);
#pragma unroll
        for (int fc = 0; fc < 4; ++fc)
            bfv[fc] = *reinterpret_cast<const bf16x8*>(&Bs[wc * 64 + fc * 16 + c][g * 8]);
#pragma unroll
        for (int fr = 0; fr < 4; ++fr)
#pragma unroll
            for (int fc = 0; fc < 4; ++fc)
                acc[fr][fc] = __builtin_amdgcn_mfma_f32_16x16x32_bf16(
                    af[fr], bfv[fc], acc[fr][fc], 0, 0, 0);
    }

    const float* bias_ptr = (which == 0) ? bq : ((which == 1) ? bk : bv);
#pragma unroll
    for (int fc = 0; fc < 4; ++fc) {
        int e = ncol0 + wc * 64 + fc * 16 + c;   // 0..767 within this weight
        float bias = bias_ptr[e];
        int h = e >> 6, d = e & 63;
#pragma unroll
        for (int fr = 0; fr < 4; ++fr) {
#pragma unroll
            for (int r = 0; r < 4; ++r) {
                int m = m0 + wr * 64 + fr * 16 + g * 4 + r;
                int b = m >> 11, s = m & 2047;
                unsigned short yb = f2b(acc[fr][fc][r] + bias);
                if (which == 2)
                    vtb[((size_t)(b * H_ + h) * D_ + d) * S_ + s] = yb;   // V^T [B,H,D,S]
                else {
                    unsigned short* dst = (which == 0) ? qb : kb;         // [B,H,S,D]
                    dst[((size_t)(b * H_ + h) * S_ + s) * D_ + d] = yb;
                }
            }
        }
    }
}

// ---------------------------------------------------------------- flash attention
// grid (S/64, B*H); 4 waves per block, wave handles 16 queries
__global__ __launch_bounds__(256) void attn_kernel(
    const unsigned short* __restrict__ qb,
    const unsigned short* __restrict__ kb,
    const unsigned short* __restrict__ vtb,
    const int* __restrict__ pad,
    unsigned short* __restrict__ ob)
{
    __shared__ __align__(16) unsigned short Plds[4][16][40];
    const int bh = blockIdx.y;
    const int b = bh / H_;
    const int t = threadIdx.x;
    const int lane = t & 63, w = t >> 6;
    const int c = lane & 15, g = lane >> 4;
    const int q0 = blockIdx.x * 64 + w * 16;
    const size_t baseQK = (size_t)bh * S_ * D_;

    // Q fragments (row = c, k-dim = d)
    bf16x8 qf[2];
#pragma unroll
    for (int ch = 0; ch < 2; ++ch)
        qf[ch] = *reinterpret_cast<const bf16x8*>(
            qb + baseQK + (size_t)(q0 + c) * D_ + ch * 32 + g * 8);

    f32x4 o[4];
#pragma unroll
    for (int fd = 0; fd < 4; ++fd) o[fd] = (f32x4){0.f, 0.f, 0.f, 0.f};
    float mrow[4], lrow[4];
#pragma unroll
    for (int r = 0; r < 4; ++r) { mrow[r] = -3.0e38f; lrow[r] = 0.f; }

    int kmax = q0 + 16; if (kmax < IMG_) kmax = IMG_;
    const int ntiles = (kmax + 31) >> 5;

    for (int kt = 0; kt < ntiles; ++kt) {
        const int k0 = kt * 32;
        // S = Q K^T for two 16-key halves
        float sv[2][4];
#pragma unroll
        for (int half = 0; half < 2; ++half) {
            bf16x8 kf0 = *reinterpret_cast<const bf16x8*>(
                kb + baseQK + (size_t)(k0 + half * 16 + c) * D_ + 0 + g * 8);
            bf16x8 kf1 = *reinterpret_cast<const bf16x8*>(
                kb + baseQK + (size_t)(k0 + half * 16 + c) * D_ + 32 + g * 8);
            f32x4 z = (f32x4){0.f, 0.f, 0.f, 0.f};
            z = __builtin_amdgcn_mfma_f32_16x16x32_bf16(qf[0], kf0, z, 0, 0, 0);
            z = __builtin_amdgcn_mfma_f32_16x16x32_bf16(qf[1], kf1, z, 0, 0, 0);
            int key = k0 + half * 16 + c;
            int pv = (key < IMG_) ? 1 : pad[b * TXT_ + (key - IMG_)];
#pragma unroll
            for (int r = 0; r < 4; ++r) {
                float s = z[r] * 0.125f;
                int q = q0 + 4 * g + r;
                bool ok = (key <= q) || (key < IMG_);
                if (!ok || pv == 0) s = NEG_;
                sv[half][r] = s;
            }
        }
        // row max across the 16 lanes of each group
        float tm[4];
#pragma unroll
        for (int r = 0; r < 4; ++r) tm[r] = fmaxf(sv[0][r], sv[1][r]);
#pragma unroll
        for (int msk = 1; msk <= 8; msk <<= 1)
#pragma unroll
            for (int r = 0; r < 4; ++r) tm[r] = fmaxf(tm[r], __shfl_xor(tm[r], msk, 64));

        float alpha[4], ps[4];
#pragma unroll
        for (int r = 0; r < 4; ++r) {
            float mnew = fmaxf(mrow[r], tm[r]);
            alpha[r] = __expf(mrow[r] - mnew);
            mrow[r] = mnew;
            ps[r] = 0.f;
        }
        // P = exp(S - m), stash transposed via LDS for the PV A-fragment
#pragma unroll
        for (int half = 0; half < 2; ++half)
#pragma unroll
            for (int r = 0; r < 4; ++r) {
                float p = __expf(sv[half][r] - mrow[r]);
                ps[r] += p;
                Plds[w][4 * g + r][half * 16 + c] = f2b(p);
            }
#pragma unroll
        for (int msk = 1; msk <= 8; msk <<= 1)
#pragma unroll
            for (int r = 0; r < 4; ++r) ps[r] += __shfl_xor(ps[r], msk, 64);
#pragma unroll
        for (int r = 0; r < 4; ++r) lrow[r] = lrow[r] * alpha[r] + ps[r];
#pragma unroll
        for (int fd = 0; fd < 4; ++fd)
#pragma unroll
            for (int r = 0; r < 4; ++r) o[fd][r] *= alpha[r];

        bf16x8 pa = *reinterpret_cast<const bf16x8*>(&Plds[w][c][g * 8]);
#pragma unroll
        for (int fd = 0; fd < 4; ++fd) {
            bf16x8 vf = *reinterpret_cast<const bf16x8*>(
                vtb + ((size_t)bh * D_ + fd * 16 + c) * S_ + k0 + g * 8);
            o[fd] = __builtin_amdgcn_mfma_f32_16x16x32_bf16(pa, vf, o[fd], 0, 0, 0);
        }
    }

    // normalize + store to [B,S,H,D] (== [B,S,E])
    const int h = bh % H_;
#pragma unroll
    for (int fd = 0; fd < 4; ++fd)
#pragma unroll
        for (int r = 0; r < 4; ++r) {
            int q = q0 + 4 * g + r;
            float val = o[fd][r] / lrow[r];
            ob[((size_t)(b * S_ + q)) * E_ + h * D_ + fd * 16 + c] = f2b(val);
        }
}

// ---------------------------------------------------------------- output projection
__global__ __launch_bounds__(256) void oproj_gemm(
    const unsigned short* __restrict__ ab,
    const unsigned short* __restrict__ wob,
    const float* __restrict__ bo,
    float* __restrict__ out)
{
    __shared__ __align__(16) unsigned short As[128][40];
    __shared__ __align__(16) unsigned short Bs[128][40];
    const int m0 = blockIdx.x * 128;
    const int n0 = blockIdx.y * 128;
    const int t = threadIdx.x;
    const int lane = t & 63, wid = t >> 6;
    const int wr = wid >> 1, wc = wid & 1;
    const int c = lane & 15, g = lane >> 4;

    f32x4 acc[4][4];
#pragma unroll
    for (int i = 0; i < 4; ++i)
#pragma unroll
        for (int j = 0; j < 4; ++j) acc[i][j] = (f32x4){0.f, 0.f, 0.f, 0.f};

    for (int k0 = 0; k0 < E_; k0 += 32) {
        __syncthreads();
#pragma unroll
        for (int p = 0; p < 2; ++p) {
            int idx = t + p * 256;
            int row = idx >> 2, ch = idx & 3;
            *reinterpret_cast<uint4*>(&As[row][ch * 8]) =
                *reinterpret_cast<const uint4*>(ab + (size_t)(m0 + row) * E_ + k0 + ch * 8);
            *reinterpret_cast<uint4*>(&Bs[row][ch * 8]) =
                *reinterpret_cast<const uint4*>(wob + (size_t)(n0 + row) * E_ + k0 + ch * 8);
        }
        __syncthreads();
        bf16x8 af[4], bfv[4];
#pragma unroll
        for (int fr = 0; fr < 4; ++fr)
            af[fr] = *reinterpret_cast<const bf16x8*>(&As[wr * 64 + fr * 16 + c][g * 8]);
#pragma unroll
        for (int fc = 0; fc < 4; ++fc)
            bfv[fc] = *reinterpret_cast<const bf16x8*>(&Bs[wc * 64 + fc * 16 + c][g * 8]);
#pragma unroll
        for (int fr = 0; fr < 4; ++fr)
#pragma unroll
            for (int fc = 0; fc < 4; ++fc)
                acc[fr][fc] = __builtin_amdgcn_mfma_f32_16x16x32_bf16(
                    af[fr], bfv[fc], acc[fr][fc], 0, 0, 0);
    }

#pragma unroll
    for (int fc = 0; fc < 4; ++fc) {
        int n = n0 + wc * 64 + fc * 16 + c;
        float bias = bo[n];
#pragma unroll
        for (int fr = 0; fr < 4; ++fr)
#pragma unroll
            for (int r = 0; r < 4; ++r) {
                int m = m0 + wr * 64 + fr * 16 + g * 4 + r;
                out[(size_t)m * E_ + n] = acc[fr][fc][r] + bias;
            }
    }
}

// ---------------------------------------------------------------- launch
extern "C" void kernel_launch(void* const* d_in, const int* in_sizes, int n_in,
                              void* d_out, int out_size, void* d_ws, size_t ws_size,
                              hipStream_t stream) {
    const float* x  = (const float*)d_in[0];
    const int* pad  = (const int*)d_in[1];
    const float* Wq = (const float*)d_in[2];
    const float* bq = (const float*)d_in[3];
    const float* Wk = (const float*)d_in[4];
    const float* bk = (const float*)d_in[5];
    const float* Wv = (const float*)d_in[6];
    const float* bv = (const float*)d_in[7];
    const float* Wo = (const float*)d_in[8];
    const float* bo = (const float*)d_in[9];
    float* out = (float*)d_out;

    const size_t NX = (size_t)B_ * S_ * E_;   // 6291456
    const size_t NW = (size_t)E_ * E_;        // 589824
    unsigned short* ws = (unsigned short*)d_ws;
    unsigned short* xb  = ws;
    unsigned short* wqb = xb + NX;
    unsigned short* wkb = wqb + NW;
    unsigned short* wvb = wkb + NW;
    unsigned short* wob = wvb + NW;
    unsigned short* qb  = wob + NW;
    unsigned short* kb  = qb + NX;
    unsigned short* vtb = kb + NX;
    unsigned short* obuf = vtb + NX;

    cvt_kernel<<<(int)(NX / 4 / 256), 256, 0, stream>>>(x, xb, (int)(NX / 4));
    cvt_kernel<<<(int)(NW / 4 / 256), 256, 0, stream>>>(Wq, wqb, (int)(NW / 4));
    cvt_kernel<<<(int)(NW / 4 / 256), 256, 0, stream>>>(Wk, wkb, (int)(NW / 4));
    cvt_kernel<<<(int)(NW / 4 / 256), 256, 0, stream>>>(Wv, wvb, (int)(NW / 4));
    cvt_kernel<<<(int)(NW / 4 / 256), 256, 0, stream>>>(Wo, wob, (int)(NW / 4));

    qkv_gemm<<<dim3(64, 18), 256, 0, stream>>>(xb, wqb, wkb, wvb, bq, bk, bv,
                                               qb, kb, vtb);
    attn_kernel<<<dim3(S_ / 64, B_ * H_), 256, 0, stream>>>(qb, kb, vtb, pad, obuf);
    oproj_gemm<<<dim3(64, 6), 256, 0, stream>>>(obuf, wob, bo, out);
}

// Round 2
// 388.173 us; speedup vs baseline: 1.2461x; 1.2461x over previous
//
#include <hip/hip_runtime.h>

#define B_ 4
#define S_ 2048
#define E_ 768
#define H_ 12
#define D_ 64
#define IMG_ 196
#define TXT_ 1852
#define NEG_ (-1e9f)

typedef __bf16 bf16x8 __attribute__((ext_vector_type(8)));
typedef float f32x4 __attribute__((ext_vector_type(4)));

__device__ __forceinline__ unsigned short f2b(float f) {
    __bf16 h = (__bf16)f;
    return __builtin_bit_cast(unsigned short, h);
}

// ---------------------------------------------------------------- conversion
__global__ __launch_bounds__(256) void cvt_kernel(const float* __restrict__ src,
                                                  unsigned short* __restrict__ dst,
                                                  int n4) {
    int i = blockIdx.x * 256 + threadIdx.x;
    if (i < n4) {
        float4 f = reinterpret_cast<const float4*>(src)[i];
        ushort4 u;
        u.x = f2b(f.x); u.y = f2b(f.y); u.z = f2b(f.z); u.w = f2b(f.w);
        reinterpret_cast<ushort4*>(dst)[i] = u;
    }
}

// ---------------------------------------------------------------- QKV GEMM
__global__ __launch_bounds__(256) void qkv_gemm(
    const unsigned short* __restrict__ xb,
    const unsigned short* __restrict__ wqb,
    const unsigned short* __restrict__ wkb,
    const unsigned short* __restrict__ wvb,
    const float* __restrict__ bq, const float* __restrict__ bk,
    const float* __restrict__ bv,
    unsigned short* __restrict__ qb, unsigned short* __restrict__ kb,
    unsigned short* __restrict__ vtb)
{
    __shared__ __align__(16) unsigned short As[128][40];
    __shared__ __align__(16) unsigned short Bs[128][40];
    const int m0 = blockIdx.x * 128;
    const int n0 = blockIdx.y * 128;
    const int which = n0 / E_;           // 0=q 1=k 2=v (tile never straddles)
    const int ncol0 = n0 % E_;
    const unsigned short* W = (which == 0) ? wqb : ((which == 1) ? wkb : wvb);
    const int t = threadIdx.x;
    const int lane = t & 63, wid = t >> 6;
    const int wr = wid >> 1, wc = wid & 1;
    const int c = lane & 15, g = lane >> 4;

    f32x4 acc[4][4];
#pragma unroll
    for (int i = 0; i < 4; ++i)
#pragma unroll
        for (int j = 0; j < 4; ++j) acc[i][j] = (f32x4){0.f, 0.f, 0.f, 0.f};

    for (int k0 = 0; k0 < E_; k0 += 32) {
        __syncthreads();
#pragma unroll
        for (int p = 0; p < 2; ++p) {
            int idx = t + p * 256;
            int row = idx >> 2, ch = idx & 3;
            *reinterpret_cast<uint4*>(&As[row][ch * 8]) =
                *reinterpret_cast<const uint4*>(xb + (size_t)(m0 + row) * E_ + k0 + ch * 8);
            *reinterpret_cast<uint4*>(&Bs[row][ch * 8]) =
                *reinterpret_cast<const uint4*>(W + (size_t)(ncol0 + row) * E_ + k0 + ch * 8);
        }
        __syncthreads();
        bf16x8 af[4], bfv[4];
#pragma unroll
        for (int fr = 0; fr < 4; ++fr)
            af[fr] = *reinterpret_cast<const bf16x8*>(&As[wr * 64 + fr * 16 + c][g * 8]);
#pragma unroll
        for (int fc = 0; fc < 4; ++fc)
            bfv[fc] = *reinterpret_cast<const bf16x8*>(&Bs[wc * 64 + fc * 16 + c][g * 8]);
#pragma unroll
        for (int fr = 0; fr < 4; ++fr)
#pragma unroll
            for (int fc = 0; fc < 4; ++fc)
                acc[fr][fc] = __builtin_amdgcn_mfma_f32_16x16x32_bf16(
                    af[fr], bfv[fc], acc[fr][fc], 0, 0, 0);
    }

    const float* bias_ptr = (which == 0) ? bq : ((which == 1) ? bk : bv);
#pragma unroll
    for (int fc = 0; fc < 4; ++fc) {
        int e = ncol0 + wc * 64 + fc * 16 + c;
        float bias = bias_ptr[e];
        int h = e >> 6, d = e & 63;
#pragma unroll
        for (int fr = 0; fr < 4; ++fr) {
#pragma unroll
            for (int r = 0; r < 4; ++r) {
                int m = m0 + wr * 64 + fr * 16 + g * 4 + r;
                int b = m >> 11, s = m & 2047;
                unsigned short yb = f2b(acc[fr][fc][r] + bias);
                if (which == 2)
                    vtb[((size_t)(b * H_ + h) * D_ + d) * S_ + s] = yb;   // V^T [B,H,D,S]
                else {
                    unsigned short* dst = (which == 0) ? qb : kb;         // [B,H,S,D]
                    dst[((size_t)(b * H_ + h) * S_ + s) * D_ + d] = yb;
                }
            }
        }
    }
}

// ---------------------------------------------------------------- flash attention
// grid (S/128, B*H); 4 waves/block, wave owns 32 queries (2 x 16-row frags)
// KVBLK=64 staged in LDS (XOR-swizzled), shared by all 4 waves.
__global__ __launch_bounds__(256) void attn_kernel(
    const unsigned short* __restrict__ qb,
    const unsigned short* __restrict__ kb,
    const unsigned short* __restrict__ vtb,
    const int* __restrict__ pad,
    unsigned short* __restrict__ ob)
{
    __shared__ __align__(16) unsigned short Ks[64 * 64];       // [key][d], swizzled
    __shared__ __align__(16) unsigned short Vs[64 * 64];       // [d][key], swizzled
    __shared__ __align__(16) unsigned short Plds[4][2][16][40];
    const int bh = blockIdx.y;
    const int b = bh / H_;
    const int t = threadIdx.x;
    const int lane = t & 63, w = t >> 6;
    const int c = lane & 15, g = lane >> 4;
    const int qbase = blockIdx.x * 128 + w * 32;
    const size_t baseQK = (size_t)bh * S_ * D_;

    // Q fragments: qf[f] rows qbase + f*16 + c
    bf16x8 qf[2][2];
#pragma unroll
    for (int f = 0; f < 2; ++f)
#pragma unroll
        for (int ch = 0; ch < 2; ++ch)
            qf[f][ch] = *reinterpret_cast<const bf16x8*>(
                qb + baseQK + (size_t)(qbase + f * 16 + c) * D_ + ch * 32 + g * 8);

    f32x4 o[2][4];
    float mrow[2][4], lrow[2][4];
#pragma unroll
    for (int f = 0; f < 2; ++f)
#pragma unroll
        for (int fd = 0; fd < 4; ++fd) o[f][fd] = (f32x4){0.f, 0.f, 0.f, 0.f};
#pragma unroll
    for (int f = 0; f < 2; ++f)
#pragma unroll
        for (int r = 0; r < 4; ++r) { mrow[f][r] = -3.0e38f; lrow[f][r] = 0.f; }

    int wkmax = qbase + 32; if (wkmax < IMG_) wkmax = IMG_;    // this wave's key bound
    int kmaxB = blockIdx.x * 128 + 128; if (kmaxB < IMG_) kmaxB = IMG_;
    const int ntiles = (kmaxB + 63) >> 6;

    for (int kt = 0; kt < ntiles; ++kt) {
        const int k0 = kt * 64;
        __syncthreads();   // previous tile's LDS reads done
        // ---- cooperative stage: K rows + V^T rows, XOR-swizzled
#pragma unroll
        for (int p = 0; p < 2; ++p) {
            int idx = t + p * 256;               // 0..511
            int row = idx >> 3, ch = idx & 7;    // 64 rows x 8 chunks of 8 elem
            int dsw = row * 64 + (((ch * 16) ^ ((row & 7) << 4)) >> 1);
            *reinterpret_cast<uint4*>(&Ks[dsw]) =
                *reinterpret_cast<const uint4*>(kb + baseQK + (size_t)(k0 + row) * D_ + ch * 8);
            *reinterpret_cast<uint4*>(&Vs[dsw]) =
                *reinterpret_cast<const uint4*>(vtb + ((size_t)bh * D_ + row) * S_ + k0 + ch * 8);
        }
        __syncthreads();

        if (k0 < wkmax) {
#pragma unroll
            for (int sub = 0; sub < 2; ++sub) {
                const int k0s = k0 + sub * 32;
                // K fragments (shared by both q-frags)
                bf16x8 kf[2][2];
#pragma unroll
                for (int h = 0; h < 2; ++h) {
                    int kr = sub * 32 + h * 16 + c;
#pragma unroll
                    for (int ch = 0; ch < 2; ++ch)
                        kf[h][ch] = *reinterpret_cast<const bf16x8*>(
                            &Ks[kr * 64 + (((ch * 64 + g * 16) ^ ((kr & 7) << 4)) >> 1)]);
                }
                // V fragments (shared by both q-frags)
                bf16x8 vf[4];
#pragma unroll
                for (int fd = 0; fd < 4; ++fd) {
                    int vd = fd * 16 + c;
                    vf[fd] = *reinterpret_cast<const bf16x8*>(
                        &Vs[vd * 64 + (((sub * 64 + g * 16) ^ ((vd & 7) << 4)) >> 1)]);
                }
                // padding mask per key half
                int pv[2];
#pragma unroll
                for (int h = 0; h < 2; ++h) {
                    int key = k0s + h * 16 + c;
                    pv[h] = (key < IMG_) ? 1 : pad[b * TXT_ + (key - IMG_)];
                }

#pragma unroll
                for (int f = 0; f < 2; ++f) {
                    float sv[2][4];
#pragma unroll
                    for (int h = 0; h < 2; ++h) {
                        f32x4 z = (f32x4){0.f, 0.f, 0.f, 0.f};
                        z = __builtin_amdgcn_mfma_f32_16x16x32_bf16(qf[f][0], kf[h][0], z, 0, 0, 0);
                        z = __builtin_amdgcn_mfma_f32_16x16x32_bf16(qf[f][1], kf[h][1], z, 0, 0, 0);
                        int key = k0s + h * 16 + c;
#pragma unroll
                        for (int r = 0; r < 4; ++r) {
                            float s = z[r] * 0.125f;
                            int q = qbase + f * 16 + 4 * g + r;
                            bool ok = (key <= q) || (key < IMG_);
                            sv[h][r] = (ok && pv[h]) ? s : NEG_;
                        }
                    }
                    // row max across 16 key-lanes
                    float tm[4];
#pragma unroll
                    for (int r = 0; r < 4; ++r) tm[r] = fmaxf(sv[0][r], sv[1][r]);
#pragma unroll
                    for (int msk = 1; msk <= 8; msk <<= 1)
#pragma unroll
                        for (int r = 0; r < 4; ++r)
                            tm[r] = fmaxf(tm[r], __shfl_xor(tm[r], msk, 64));

                    float big = tm[0] - mrow[f][0];
#pragma unroll
                    for (int r = 1; r < 4; ++r) big = fmaxf(big, tm[r] - mrow[f][r]);
                    float ps[4];
                    if (__all(big <= 8.f)) {
                        // defer-max: keep old m, no rescale (P bounded by e^8)
#pragma unroll
                        for (int r = 0; r < 4; ++r) ps[r] = 0.f;
#pragma unroll
                        for (int h = 0; h < 2; ++h)
#pragma unroll
                            for (int r = 0; r < 4; ++r) {
                                float p = __expf(sv[h][r] - mrow[f][r]);
                                ps[r] += p;
                                Plds[w][f][4 * g + r][h * 16 + c] = f2b(p);
                            }
#pragma unroll
                        for (int msk = 1; msk <= 8; msk <<= 1)
#pragma unroll
                            for (int r = 0; r < 4; ++r) ps[r] += __shfl_xor(ps[r], msk, 64);
#pragma unroll
                        for (int r = 0; r < 4; ++r) lrow[f][r] += ps[r];
                    } else {
#pragma unroll
                        for (int r = 0; r < 4; ++r) {
                            float mnew = fmaxf(mrow[f][r], tm[r]);
                            float alpha = __expf(mrow[f][r] - mnew);
                            mrow[f][r] = mnew;
                            lrow[f][r] *= alpha;
#pragma unroll
                            for (int fd = 0; fd < 4; ++fd) o[f][fd][r] *= alpha;
                            ps[r] = 0.f;
                        }
#pragma unroll
                        for (int h = 0; h < 2; ++h)
#pragma unroll
                            for (int r = 0; r < 4; ++r) {
                                float p = __expf(sv[h][r] - mrow[f][r]);
                                ps[r] += p;
                                Plds[w][f][4 * g + r][h * 16 + c] = f2b(p);
                            }
#pragma unroll
                        for (int msk = 1; msk <= 8; msk <<= 1)
#pragma unroll
                            for (int r = 0; r < 4; ++r) ps[r] += __shfl_xor(ps[r], msk, 64);
#pragma unroll
                        for (int r = 0; r < 4; ++r) lrow[f][r] += ps[r];
                    }
                }
                // PV for both q-frags
#pragma unroll
                for (int f = 0; f < 2; ++f) {
                    bf16x8 pa = *reinterpret_cast<const bf16x8*>(&Plds[w][f][c][g * 8]);
#pragma unroll
                    for (int fd = 0; fd < 4; ++fd)
                        o[f][fd] = __builtin_amdgcn_mfma_f32_16x16x32_bf16(
                            pa, vf[fd], o[f][fd], 0, 0, 0);
                }
            }
        }
    }

    // normalize + store to [B,S,H,D] (== [B,S,E])
    const int h = bh % H_;
#pragma unroll
    for (int f = 0; f < 2; ++f)
#pragma unroll
        for (int fd = 0; fd < 4; ++fd)
#pragma unroll
            for (int r = 0; r < 4; ++r) {
                int q = qbase + f * 16 + 4 * g + r;
                float val = o[f][fd][r] / lrow[f][r];
                ob[((size_t)(b * S_ + q)) * E_ + h * D_ + fd * 16 + c] = f2b(val);
            }
}

// ---------------------------------------------------------------- output projection
__global__ __launch_bounds__(256) void oproj_gemm(
    const unsigned short* __restrict__ ab,
    const unsigned short* __restrict__ wob,
    const float* __restrict__ bo,
    float* __restrict__ out)
{
    __shared__ __align__(16) unsigned short As[128][40];
    __shared__ __align__(16) unsigned short Bs[128][40];
    const int m0 = blockIdx.x * 128;
    const int n0 = blockIdx.y * 128;
    const int t = threadIdx.x;
    const int lane = t & 63, wid = t >> 6;
    const int wr = wid >> 1, wc = wid & 1;
    const int c = lane & 15, g = lane >> 4;

    f32x4 acc[4][4];
#pragma unroll
    for (int i = 0; i < 4; ++i)
#pragma unroll
        for (int j = 0; j < 4; ++j) acc[i][j] = (f32x4){0.f, 0.f, 0.f, 0.f};

    for (int k0 = 0; k0 < E_; k0 += 32) {
        __syncthreads();
#pragma unroll
        for (int p = 0; p < 2; ++p) {
            int idx = t + p * 256;
            int row = idx >> 2, ch = idx & 3;
            *reinterpret_cast<uint4*>(&As[row][ch * 8]) =
                *reinterpret_cast<const uint4*>(ab + (size_t)(m0 + row) * E_ + k0 + ch * 8);
            *reinterpret_cast<uint4*>(&Bs[row][ch * 8]) =
                *reinterpret_cast<const uint4*>(wob + (size_t)(n0 + row) * E_ + k0 + ch * 8);
        }
        __syncthreads();
        bf16x8 af[4], bfv[4];
#pragma unroll
        for (int fr = 0; fr < 4; ++fr)
            af[fr] = *reinterpret_cast<const bf16x8*>(&As[wr * 64 + fr * 16 + c][g * 8]);
#pragma unroll
        for (int fc = 0; fc < 4; ++fc)
            bfv[fc] = *reinterpret_cast<const bf16x8*>(&Bs[wc * 64 + fc * 16 + c][g * 8]);
#pragma unroll
        for (int fr = 0; fr < 4; ++fr)
#pragma unroll
            for (int fc = 0; fc < 4; ++fc)
                acc[fr][fc] = __builtin_amdgcn_mfma_f32_16x16x32_bf16(
                    af[fr], bfv[fc], acc[fr][fc], 0, 0, 0);
    }

#pragma unroll
    for (int fc = 0; fc < 4; ++fc) {
        int n = n0 + wc * 64 + fc * 16 + c;
        float bias = bo[n];
#pragma unroll
        for (int fr = 0; fr < 4; ++fr)
#pragma unroll
            for (int r = 0; r < 4; ++r) {
                int m = m0 + wr * 64 + fr * 16 + g * 4 + r;
                out[(size_t)m * E_ + n] = acc[fr][fc][r] + bias;
            }
    }
}

// ---------------------------------------------------------------- launch
extern "C" void kernel_launch(void* const* d_in, const int* in_sizes, int n_in,
                              void* d_out, int out_size, void* d_ws, size_t ws_size,
                              hipStream_t stream) {
    const float* x  = (const float*)d_in[0];
    const int* pad  = (const int*)d_in[1];
    const float* Wq = (const float*)d_in[2];
    const float* bq = (const float*)d_in[3];
    const float* Wk = (const float*)d_in[4];
    const float* bk = (const float*)d_in[5];
    const float* Wv = (const float*)d_in[6];
    const float* bv = (const float*)d_in[7];
    const float* Wo = (const float*)d_in[8];
    const float* bo = (const float*)d_in[9];
    float* out = (float*)d_out;

    const size_t NX = (size_t)B_ * S_ * E_;   // 6291456
    const size_t NW = (size_t)E_ * E_;        // 589824
    unsigned short* ws = (unsigned short*)d_ws;
    unsigned short* xb  = ws;
    unsigned short* wqb = xb + NX;
    unsigned short* wkb = wqb + NW;
    unsigned short* wvb = wkb + NW;
    unsigned short* wob = wvb + NW;
    unsigned short* qb  = wob + NW;
    unsigned short* kb  = qb + NX;
    unsigned short* vtb = kb + NX;
    unsigned short* obuf = vtb + NX;

    cvt_kernel<<<(int)(NX / 4 / 256), 256, 0, stream>>>(x, xb, (int)(NX / 4));
    cvt_kernel<<<(int)(NW / 4 / 256), 256, 0, stream>>>(Wq, wqb, (int)(NW / 4));
    cvt_kernel<<<(int)(NW / 4 / 256), 256, 0, stream>>>(Wk, wkb, (int)(NW / 4));
    cvt_kernel<<<(int)(NW / 4 / 256), 256, 0, stream>>>(Wv, wvb, (int)(NW / 4));
    cvt_kernel<<<(int)(NW / 4 / 256), 256, 0, stream>>>(Wo, wob, (int)(NW / 4));

    qkv_gemm<<<dim3(64, 18), 256, 0, stream>>>(xb, wqb, wkb, wvb, bq, bk, bv,
                                               qb, kb, vtb);
    attn_kernel<<<dim3(S_ / 128, B_ * H_), 256, 0, stream>>>(qb, kb, vtb, pad, obuf);
    oproj_gemm<<<dim3(64, 6), 256, 0, stream>>>(obuf, wob, bo, out);
}

// Round 3
// 204.749 us; speedup vs baseline: 2.3624x; 1.8958x over previous
//
#include <hip/hip_runtime.h>

#define B_ 4
#define S_ 2048
#define E_ 768
#define H_ 12
#define D_ 64
#define IMG_ 196
#define TXT_ 1852
#define NEG_ (-1e9f)

typedef __bf16 bf16x8 __attribute__((ext_vector_type(8)));
typedef float f32x4 __attribute__((ext_vector_type(4)));
typedef float f32x16 __attribute__((ext_vector_type(16)));

__device__ __forceinline__ unsigned short f2b(float f) {
    __bf16 h = (__bf16)f;
    return __builtin_bit_cast(unsigned short, h);
}
__device__ __forceinline__ unsigned int pack2(float lo, float hi) {
    return (unsigned int)f2b(lo) | ((unsigned int)f2b(hi) << 16);
}

// ---------------------------------------------------------------- conversion
__global__ __launch_bounds__(256) void cvt_kernel(const float* __restrict__ src,
                                                  unsigned short* __restrict__ dst,
                                                  int n4) {
    int i = blockIdx.x * 256 + threadIdx.x;
    if (i < n4) {
        float4 f = reinterpret_cast<const float4*>(src)[i];
        ushort4 u;
        u.x = f2b(f.x); u.y = f2b(f.y); u.z = f2b(f.z); u.w = f2b(f.w);
        reinterpret_cast<ushort4*>(dst)[i] = u;
    }
}

// padneg[b][s] = 0 if key s is pad-valid, -1e9 if padded out
__global__ __launch_bounds__(256) void padneg_kernel(const int* __restrict__ pad,
                                                     float* __restrict__ padneg) {
    int i = blockIdx.x * 256 + threadIdx.x;      // over B*S
    if (i < B_ * S_) {
        int b = i >> 11, s = i & 2047;
        float v = 0.f;
        if (s >= IMG_) v = pad[b * TXT_ + (s - IMG_)] ? 0.f : NEG_;
        padneg[i] = v;
    }
}

// ---------------------------------------------------------------- QKV GEMM
__global__ __launch_bounds__(256) void qkv_gemm(
    const unsigned short* __restrict__ xb,
    const unsigned short* __restrict__ wqb,
    const unsigned short* __restrict__ wkb,
    const unsigned short* __restrict__ wvb,
    const float* __restrict__ bq, const float* __restrict__ bk,
    const float* __restrict__ bv,
    unsigned short* __restrict__ qb, unsigned short* __restrict__ kb,
    unsigned short* __restrict__ vtb)
{
    __shared__ __align__(16) unsigned short As[128][40];
    __shared__ __align__(16) unsigned short Bs[128][40];
    const int m0 = blockIdx.x * 128;
    const int n0 = blockIdx.y * 128;
    const int which = n0 / E_;
    const int ncol0 = n0 % E_;
    const unsigned short* W = (which == 0) ? wqb : ((which == 1) ? wkb : wvb);
    const int t = threadIdx.x;
    const int lane = t & 63, wid = t >> 6;
    const int wr = wid >> 1, wc = wid & 1;
    const int c = lane & 15, g = lane >> 4;

    f32x4 acc[4][4];
#pragma unroll
    for (int i = 0; i < 4; ++i)
#pragma unroll
        for (int j = 0; j < 4; ++j) acc[i][j] = (f32x4){0.f, 0.f, 0.f, 0.f};

    for (int k0 = 0; k0 < E_; k0 += 32) {
        __syncthreads();
#pragma unroll
        for (int p = 0; p < 2; ++p) {
            int idx = t + p * 256;
            int row = idx >> 2, ch = idx & 3;
            *reinterpret_cast<uint4*>(&As[row][ch * 8]) =
                *reinterpret_cast<const uint4*>(xb + (size_t)(m0 + row) * E_ + k0 + ch * 8);
            *reinterpret_cast<uint4*>(&Bs[row][ch * 8]) =
                *reinterpret_cast<const uint4*>(W + (size_t)(ncol0 + row) * E_ + k0 + ch * 8);
        }
        __syncthreads();
        bf16x8 af[4], bfv[4];
#pragma unroll
        for (int fr = 0; fr < 4; ++fr)
            af[fr] = *reinterpret_cast<const bf16x8*>(&As[wr * 64 + fr * 16 + c][g * 8]);
#pragma unroll
        for (int fc = 0; fc < 4; ++fc)
            bfv[fc] = *reinterpret_cast<const bf16x8*>(&Bs[wc * 64 + fc * 16 + c][g * 8]);
#pragma unroll
        for (int fr = 0; fr < 4; ++fr)
#pragma unroll
            for (int fc = 0; fc < 4; ++fc)
                acc[fr][fc] = __builtin_amdgcn_mfma_f32_16x16x32_bf16(
                    af[fr], bfv[fc], acc[fr][fc], 0, 0, 0);
    }

    const float* bias_ptr = (which == 0) ? bq : ((which == 1) ? bk : bv);
#pragma unroll
    for (int fc = 0; fc < 4; ++fc) {
        int e = ncol0 + wc * 64 + fc * 16 + c;
        float bias = bias_ptr[e];
        int h = e >> 6, d = e & 63;
#pragma unroll
        for (int fr = 0; fr < 4; ++fr) {
#pragma unroll
            for (int r = 0; r < 4; ++r) {
                int m = m0 + wr * 64 + fr * 16 + g * 4 + r;
                int b = m >> 11, s = m & 2047;
                unsigned short yb = f2b(acc[fr][fc][r] + bias);
                if (which == 2)
                    vtb[((size_t)(b * H_ + h) * D_ + d) * S_ + s] = yb;   // V^T [B,H,D,S]
                else {
                    unsigned short* dst = (which == 0) ? qb : kb;         // [B,H,S,D]
                    dst[((size_t)(b * H_ + h) * S_ + s) * D_ + d] = yb;
                }
            }
        }
    }
}

// ---------------------------------------------------------------- flash attention
// One wave per (bh, 32-query tile). Swapped QK^T (32x32x16): C col = query.
// Softmax fully lane-local; P redistributed to PV B-fragment via 4 shfl_xor(32).
// No K/V staging (L2-resident), no barriers after the pad-LDS fill.
__global__ __launch_bounds__(256) void attn_kernel(
    const unsigned short* __restrict__ qb,
    const unsigned short* __restrict__ kb,
    const unsigned short* __restrict__ vtb,
    const float* __restrict__ padneg,
    unsigned short* __restrict__ ob)
{
    __shared__ float pneg[S_];
    const int flat = blockIdx.x + 16 * blockIdx.y;   // 0..767
    const int xcd = flat & 7, idx = flat >> 3;       // XCD-locality remap (T1)
    const int bh = xcd * 6 + (idx >> 4);             // one head stays on one XCD
    const int qg = idx & 15;
    const int b = bh / H_, hh = bh % H_;
    const int t = threadIdx.x;

    {   // pad mask -> LDS (only barrier in the kernel)
        const float4* src = reinterpret_cast<const float4*>(padneg + b * S_);
        float4* dst = reinterpret_cast<float4*>(pneg);
        dst[t] = src[t];
        dst[t + 256] = src[t + 256];
    }
    __syncthreads();

    const int lane = t & 63, w = t >> 6;
    const int h = lane >> 5, ql = lane & 31;
    // balance pairing: block handles qtiles {2qg, 2qg+1, 63-2qg, 62-2qg}
    const int low = 2 * qg + (w & 1);
    const int qt = (w < 2) ? low : 63 - low;
    const int qbase = qt * 32;
    const int q = qbase + ql;
    const size_t baseQK = (size_t)bh * S_ * D_;

    // Q fragment: B[k=d][col=q], lane holds Q[q=ql][dc*16 + h*8 + j]
    bf16x8 qf[4];
#pragma unroll
    for (int dc = 0; dc < 4; ++dc)
        qf[dc] = *reinterpret_cast<const bf16x8*>(
            qb + baseQK + (size_t)q * D_ + dc * 16 + h * 8);

    f32x16 oa0, oa1;            // O^T: col=q, row=d within 32-d block
#pragma unroll
    for (int r = 0; r < 16; ++r) { oa0[r] = 0.f; oa1[r] = 0.f; }
    float mr = -3.0e38f, lr = 0.f;

    int kmax = qbase + 32; if (kmax < IMG_) kmax = IMG_;
    const int ntiles = (kmax + 31) >> 5;

    for (int kt = 0; kt < ntiles; ++kt) {
        const int k0 = kt * 32;
        // K fragment: A[row=key][k=d], lane holds K[k0+ql][dc*16 + h*8 + j]
        bf16x8 kf[4];
#pragma unroll
        for (int dc = 0; dc < 4; ++dc)
            kf[dc] = *reinterpret_cast<const bf16x8*>(
                kb + baseQK + (size_t)(k0 + ql) * D_ + dc * 16 + h * 8);

        f32x16 s;
#pragma unroll
        for (int r = 0; r < 16; ++r) s[r] = 0.f;
#pragma unroll
        for (int dc = 0; dc < 4; ++dc)
            s = __builtin_amdgcn_mfma_f32_32x32x16_bf16(kf[dc], qf[dc], s, 0, 0, 0);
        // s[r] = score for key = k0 + (r&3) + 8*(r>>2) + 4*h, query = q

        float pna[16];
        *reinterpret_cast<float4*>(&pna[0])  = *reinterpret_cast<const float4*>(&pneg[k0 + 0  + 4 * h]);
        *reinterpret_cast<float4*>(&pna[4])  = *reinterpret_cast<const float4*>(&pneg[k0 + 8  + 4 * h]);
        *reinterpret_cast<float4*>(&pna[8])  = *reinterpret_cast<const float4*>(&pneg[k0 + 16 + 4 * h]);
        *reinterpret_cast<float4*>(&pna[12]) = *reinterpret_cast<const float4*>(&pneg[k0 + 24 + 4 * h]);
#pragma unroll
        for (int r = 0; r < 16; ++r) s[r] = fmaf(s[r], 0.125f, pna[r]);

        if (kt == ntiles - 1) {   // causal needed only on the diagonal/terminal tile
#pragma unroll
            for (int r = 0; r < 16; ++r) {
                int key = k0 + (r & 3) + 8 * (r >> 2) + 4 * h;
                if (!((key <= q) || (key < IMG_))) s[r] = NEG_;
            }
        }

        // row max: 15 in-reg max + 1 cross-half swap
        float t0 = fmaxf(fmaxf(s[0], s[1]), fmaxf(s[2], s[3]));
        float t1 = fmaxf(fmaxf(s[4], s[5]), fmaxf(s[6], s[7]));
        float t2 = fmaxf(fmaxf(s[8], s[9]), fmaxf(s[10], s[11]));
        float t3 = fmaxf(fmaxf(s[12], s[13]), fmaxf(s[14], s[15]));
        float tm = fmaxf(fmaxf(t0, t1), fmaxf(t2, t3));
        tm = fmaxf(tm, __shfl_xor(tm, 32, 64));

        // defer-max (T13, THR=8)
        if (!__all(tm - mr <= 8.f)) {
            float mnew = fmaxf(mr, tm);
            float alpha = __expf(mr - mnew);
            mr = mnew; lr *= alpha;
#pragma unroll
            for (int r = 0; r < 16; ++r) { oa0[r] *= alpha; oa1[r] *= alpha; }
        }

        float p[16];
#pragma unroll
        for (int r = 0; r < 16; ++r) p[r] = __expf(s[r] - mr);
        float a0 = (p[0] + p[1]) + (p[2] + p[3]);
        float a1 = (p[4] + p[5]) + (p[6] + p[7]);
        float a2 = (p[8] + p[9]) + (p[10] + p[11]);
        float a3 = (p[12] + p[13]) + (p[14] + p[15]);
        float ss = (a0 + a1) + (a2 + a3);
        ss += __shfl_xor(ss, 32, 64);
        lr += ss;

        // pack P groups (keys gg*8 + 4h + {0..3}) as bf16 pairs
        unsigned int pka0 = pack2(p[0], p[1]),   pkb0 = pack2(p[2], p[3]);
        unsigned int pka1 = pack2(p[4], p[5]),   pkb1 = pack2(p[6], p[7]);
        unsigned int pka2 = pack2(p[8], p[9]),   pkb2 = pack2(p[10], p[11]);
        unsigned int pka3 = pack2(p[12], p[13]), pkb3 = pack2(p[14], p[15]);

#pragma unroll
        for (int m = 0; m < 2; ++m) {
            // PV B-fragment for keys m*16..m*16+15: lane needs keys m*16+8h+{0..7}.
            // own-kept group = 2m+h, partner-needed group = 2m+(1-h).
            unsigned int keep0 = h ? (m ? pka3 : pka1) : (m ? pka2 : pka0);
            unsigned int keep1 = h ? (m ? pkb3 : pkb1) : (m ? pkb2 : pkb0);
            unsigned int send0 = h ? (m ? pka2 : pka0) : (m ? pka3 : pka1);
            unsigned int send1 = h ? (m ? pkb2 : pkb0) : (m ? pkb3 : pkb1);
            unsigned int x0 = (unsigned int)__shfl_xor((int)send0, 32, 64);
            unsigned int x1 = (unsigned int)__shfl_xor((int)send1, 32, 64);
            uint4 fr;
            fr.x = h ? x0 : keep0;
            fr.y = h ? x1 : keep1;
            fr.z = h ? keep0 : x0;
            fr.w = h ? keep1 : x1;
            bf16x8 pb = __builtin_bit_cast(bf16x8, fr);
            bf16x8 vf0 = *reinterpret_cast<const bf16x8*>(
                vtb + ((size_t)bh * D_ + ql) * S_ + k0 + m * 16 + h * 8);
            bf16x8 vf1 = *reinterpret_cast<const bf16x8*>(
                vtb + ((size_t)bh * D_ + 32 + ql) * S_ + k0 + m * 16 + h * 8);
            oa0 = __builtin_amdgcn_mfma_f32_32x32x16_bf16(vf0, pb, oa0, 0, 0, 0);
            oa1 = __builtin_amdgcn_mfma_f32_32x32x16_bf16(vf1, pb, oa1, 0, 0, 0);
        }
    }

    // normalize + store to [B,S,E]; O^T row d = gg*8 + 4h + (reg&3)
    float inv = 1.f / lr;
    unsigned short* orow = ob + ((size_t)(b * S_ + q)) * E_ + hh * D_;
#pragma unroll
    for (int gg = 0; gg < 4; ++gg) {
        int d0 = gg * 8 + 4 * h;
        uint2 s0, s1;
        s0.x = pack2(oa0[4 * gg] * inv, oa0[4 * gg + 1] * inv);
        s0.y = pack2(oa0[4 * gg + 2] * inv, oa0[4 * gg + 3] * inv);
        s1.x = pack2(oa1[4 * gg] * inv, oa1[4 * gg + 1] * inv);
        s1.y = pack2(oa1[4 * gg + 2] * inv, oa1[4 * gg + 3] * inv);
        *reinterpret_cast<uint2*>(orow + d0) = s0;
        *reinterpret_cast<uint2*>(orow + 32 + d0) = s1;
    }
}

// ---------------------------------------------------------------- output projection
__global__ __launch_bounds__(256) void oproj_gemm(
    const unsigned short* __restrict__ ab,
    const unsigned short* __restrict__ wob,
    const float* __restrict__ bo,
    float* __restrict__ out)
{
    __shared__ __align__(16) unsigned short As[128][40];
    __shared__ __align__(16) unsigned short Bs[128][40];
    const int m0 = blockIdx.x * 128;
    const int n0 = blockIdx.y * 128;
    const int t = threadIdx.x;
    const int lane = t & 63, wid = t >> 6;
    const int wr = wid >> 1, wc = wid & 1;
    const int c = lane & 15, g = lane >> 4;

    f32x4 acc[4][4];
#pragma unroll
    for (int i = 0; i < 4; ++i)
#pragma unroll
        for (int j = 0; j < 4; ++j) acc[i][j] = (f32x4){0.f, 0.f, 0.f, 0.f};

    for (int k0 = 0; k0 < E_; k0 += 32) {
        __syncthreads();
#pragma unroll
        for (int p = 0; p < 2; ++p) {
            int idx = t + p * 256;
            int row = idx >> 2, ch = idx & 3;
            *reinterpret_cast<uint4*>(&As[row][ch * 8]) =
                *reinterpret_cast<const uint4*>(ab + (size_t)(m0 + row) * E_ + k0 + ch * 8);
            *reinterpret_cast<uint4*>(&Bs[row][ch * 8]) =
                *reinterpret_cast<const uint4*>(wob + (size_t)(n0 + row) * E_ + k0 + ch * 8);
        }
        __syncthreads();
        bf16x8 af[4], bfv[4];
#pragma unroll
        for (int fr = 0; fr < 4; ++fr)
            af[fr] = *reinterpret_cast<const bf16x8*>(&As[wr * 64 + fr * 16 + c][g * 8]);
#pragma unroll
        for (int fc = 0; fc < 4; ++fc)
            bfv[fc] = *reinterpret_cast<const bf16x8*>(&Bs[wc * 64 + fc * 16 + c][g * 8]);
#pragma unroll
        for (int fr = 0; fr < 4; ++fr)
#pragma unroll
            for (int fc = 0; fc < 4; ++fc)
                acc[fr][fc] = __builtin_amdgcn_mfma_f32_16x16x32_bf16(
                    af[fr], bfv[fc], acc[fr][fc], 0, 0, 0);
    }

#pragma unroll
    for (int fc = 0; fc < 4; ++fc) {
        int n = n0 + wc * 64 + fc * 16 + c;
        float bias = bo[n];
#pragma unroll
        for (int fr = 0; fr < 4; ++fr)
#pragma unroll
            for (int r = 0; r < 4; ++r) {
                int m = m0 + wr * 64 + fr * 16 + g * 4 + r;
                out[(size_t)m * E_ + n] = acc[fr][fc][r] + bias;
            }
    }
}

// ---------------------------------------------------------------- launch
extern "C" void kernel_launch(void* const* d_in, const int* in_sizes, int n_in,
                              void* d_out, int out_size, void* d_ws, size_t ws_size,
                              hipStream_t stream) {
    const float* x  = (const float*)d_in[0];
    const int* pad  = (const int*)d_in[1];
    const float* Wq = (const float*)d_in[2];
    const float* bq = (const float*)d_in[3];
    const float* Wk = (const float*)d_in[4];
    const float* bk = (const float*)d_in[5];
    const float* Wv = (const float*)d_in[6];
    const float* bv = (const float*)d_in[7];
    const float* Wo = (const float*)d_in[8];
    const float* bo = (const float*)d_in[9];
    float* out = (float*)d_out;

    const size_t NX = (size_t)B_ * S_ * E_;   // 6291456
    const size_t NW = (size_t)E_ * E_;        // 589824
    unsigned short* ws = (unsigned short*)d_ws;
    unsigned short* xb  = ws;
    unsigned short* wqb = xb + NX;
    unsigned short* wkb = wqb + NW;
    unsigned short* wvb = wkb + NW;
    unsigned short* wob = wvb + NW;
    unsigned short* qb  = wob + NW;
    unsigned short* kb  = qb + NX;
    unsigned short* vtb = kb + NX;
    unsigned short* obuf = vtb + NX;
    float* padneg = (float*)(obuf + NX);      // B*S floats

    cvt_kernel<<<(int)(NX / 4 / 256), 256, 0, stream>>>(x, xb, (int)(NX / 4));
    cvt_kernel<<<(int)(NW / 4 / 256), 256, 0, stream>>>(Wq, wqb, (int)(NW / 4));
    cvt_kernel<<<(int)(NW / 4 / 256), 256, 0, stream>>>(Wk, wkb, (int)(NW / 4));
    cvt_kernel<<<(int)(NW / 4 / 256), 256, 0, stream>>>(Wv, wvb, (int)(NW / 4));
    cvt_kernel<<<(int)(NW / 4 / 256), 256, 0, stream>>>(Wo, wob, (int)(NW / 4));
    padneg_kernel<<<(B_ * S_) / 256, 256, 0, stream>>>(pad, padneg);

    qkv_gemm<<<dim3(64, 18), 256, 0, stream>>>(xb, wqb, wkb, wvb, bq, bk, bv,
                                               qb, kb, vtb);
    attn_kernel<<<dim3(16, 48), 256, 0, stream>>>(qb, kb, vtb, padneg, obuf);
    oproj_gemm<<<dim3(64, 6), 256, 0, stream>>>(obuf, wob, bo, out);
}

// Round 4
// 201.314 us; speedup vs baseline: 2.4027x; 1.0171x over previous
//
#include <hip/hip_runtime.h>

#define B_ 4
#define S_ 2048
#define E_ 768
#define H_ 12
#define D_ 64
#define IMG_ 196
#define TXT_ 1852
#define NEG_ (-1e9f)

typedef __bf16 bf16x8 __attribute__((ext_vector_type(8)));
typedef float f32x4 __attribute__((ext_vector_type(4)));
typedef float f32x16 __attribute__((ext_vector_type(16)));

__device__ __forceinline__ unsigned short f2b(float f) {
    __bf16 h = (__bf16)f;
    return __builtin_bit_cast(unsigned short, h);
}
__device__ __forceinline__ unsigned int pack2(float lo, float hi) {
    return (unsigned int)f2b(lo) | ((unsigned int)f2b(hi) << 16);
}
// async global->LDS, 16B per lane; LDS dest wave-uniform base + lane*16
__device__ __forceinline__ void gload16(const unsigned short* g, unsigned short* l) {
    __builtin_amdgcn_global_load_lds(
        (const __attribute__((address_space(1))) unsigned int*)g,
        (__attribute__((address_space(3))) unsigned int*)l, 16, 0, 0);
}

// ---------------------------------------------------------------- conversion
__global__ __launch_bounds__(256) void cvt_kernel(const float* __restrict__ src,
                                                  unsigned short* __restrict__ dst,
                                                  int n4) {
    int i = blockIdx.x * 256 + threadIdx.x;
    if (i < n4) {
        float4 f = reinterpret_cast<const float4*>(src)[i];
        ushort4 u;
        u.x = f2b(f.x); u.y = f2b(f.y); u.z = f2b(f.z); u.w = f2b(f.w);
        reinterpret_cast<ushort4*>(dst)[i] = u;
    }
}

// padneg[b][s] = 0 if key s is pad-valid, -1e9 if padded out
__global__ __launch_bounds__(256) void padneg_kernel(const int* __restrict__ pad,
                                                     float* __restrict__ padneg) {
    int i = blockIdx.x * 256 + threadIdx.x;      // over B*S
    if (i < B_ * S_) {
        int b = i >> 11, s = i & 2047;
        float v = 0.f;
        if (s >= IMG_) v = pad[b * TXT_ + (s - IMG_)] ? 0.f : NEG_;
        padneg[i] = v;
    }
}

// ---------------------------------------------------------------- QKV GEMM
// 128x128 tile, BK=64, global_load_lds staging with XOR-swizzled source/reads.
__global__ __launch_bounds__(256) void qkv_gemm(
    const unsigned short* __restrict__ xb,
    const unsigned short* __restrict__ wqb,
    const unsigned short* __restrict__ wkb,
    const unsigned short* __restrict__ wvb,
    const float* __restrict__ bq, const float* __restrict__ bk,
    const float* __restrict__ bv,
    unsigned short* __restrict__ qb, unsigned short* __restrict__ kb,
    unsigned short* __restrict__ vtb)
{
    __shared__ __align__(16) unsigned short As[128 * 64];
    __shared__ __align__(16) unsigned short Bs[128 * 64];
    const int m0 = blockIdx.x * 128;
    const int n0 = blockIdx.y * 128;
    const int which = n0 / E_;
    const int ncol0 = n0 % E_;
    const unsigned short* W = (which == 0) ? wqb : ((which == 1) ? wkb : wvb);
    const int t = threadIdx.x;
    const int lane = t & 63, wid = t >> 6;
    const int wr = wid >> 1, wc = wid & 1;
    const int c = lane & 15, g = lane >> 4;
    const int srow = lane >> 3;            // row within 8-row chunk
    const int sslot = (lane & 7) ^ srow;   // pre-swizzled source 16B-slot

    f32x4 acc[4][4];
#pragma unroll
    for (int i = 0; i < 4; ++i)
#pragma unroll
        for (int j = 0; j < 4; ++j) acc[i][j] = (f32x4){0.f, 0.f, 0.f, 0.f};

    for (int k0 = 0; k0 < E_; k0 += 64) {
        __syncthreads();   // prev-iter LDS reads done
#pragma unroll
        for (int j = 0; j < 8; ++j) {
            int chunk = wid * 8 + j;       // 0..31 (wave-uniform)
            int isB = chunk >> 4;
            int ch = chunk & 15;
            int row = ch * 8 + srow;
            const unsigned short* src =
                (isB ? W + (size_t)(ncol0 + row) * E_
                     : xb + (size_t)(m0 + row) * E_) + k0 + sslot * 8;
            unsigned short* dst = (isB ? Bs : As) + ch * 512;
            gload16(src, dst);
        }
        __syncthreads();   // staging visible (vmcnt drained by barrier)

        bf16x8 af[2][4], bfv[2][4];
#pragma unroll
        for (int kk = 0; kk < 2; ++kk) {
#pragma unroll
            for (int fr = 0; fr < 4; ++fr) {
                int row = wr * 64 + fr * 16 + c;
                af[kk][fr] = *reinterpret_cast<const bf16x8*>(
                    &As[row * 64 + (((kk * 4 + g) ^ (row & 7)) * 8)]);
            }
#pragma unroll
            for (int fc = 0; fc < 4; ++fc) {
                int row = wc * 64 + fc * 16 + c;
                bfv[kk][fc] = *reinterpret_cast<const bf16x8*>(
                    &Bs[row * 64 + (((kk * 4 + g) ^ (row & 7)) * 8)]);
            }
        }
#pragma unroll
        for (int kk = 0; kk < 2; ++kk)
#pragma unroll
            for (int fr = 0; fr < 4; ++fr)
#pragma unroll
                for (int fc = 0; fc < 4; ++fc)
                    acc[fr][fc] = __builtin_amdgcn_mfma_f32_16x16x32_bf16(
                        af[kk][fr], bfv[kk][fc], acc[fr][fc], 0, 0, 0);
    }

    const float* bias_ptr = (which == 0) ? bq : ((which == 1) ? bk : bv);
#pragma unroll
    for (int fc = 0; fc < 4; ++fc) {
        int e = ncol0 + wc * 64 + fc * 16 + c;
        float bias = bias_ptr[e];
        int h = e >> 6, d = e & 63;
#pragma unroll
        for (int fr = 0; fr < 4; ++fr) {
#pragma unroll
            for (int r = 0; r < 4; ++r) {
                int m = m0 + wr * 64 + fr * 16 + g * 4 + r;
                int b = m >> 11, s = m & 2047;
                unsigned short yb = f2b(acc[fr][fc][r] + bias);
                if (which == 2)
                    vtb[((size_t)(b * H_ + h) * D_ + d) * S_ + s] = yb;   // V^T [B,H,D,S]
                else {
                    unsigned short* dst = (which == 0) ? qb : kb;         // [B,H,S,D]
                    dst[((size_t)(b * H_ + h) * S_ + s) * D_ + d] = yb;
                }
            }
        }
    }
}

// ---------------------------------------------------------------- flash attention
// Split-K: each (bh, 32-query tile) handled by TWO waves (key tiles by parity),
// merged once via LDS. Swapped QK^T (32x32x16): C col = query; softmax lane-local.
__global__ __launch_bounds__(256) void attn_kernel(
    const unsigned short* __restrict__ qb,
    const unsigned short* __restrict__ kb,
    const unsigned short* __restrict__ vtb,
    const float* __restrict__ padneg,
    unsigned short* __restrict__ ob)
{
    __shared__ float pneg[S_];
    __shared__ float exch[2][34][64];
    const int flat = blockIdx.x;                 // 0..1535
    const int xcd = flat & 7, idx = flat >> 3;   // XCD-locality remap (T1)
    const int bh = xcd * 6 + (idx >> 5);         // one head stays on one XCD
    const int qg = idx & 31;
    const int b = bh / H_, hh = bh % H_;
    const int t = threadIdx.x;

    {   // pad mask -> LDS
        const float4* src = reinterpret_cast<const float4*>(padneg + b * S_);
        float4* dst = reinterpret_cast<float4*>(pneg);
        dst[t] = src[t];
        dst[t + 256] = src[t + 256];
    }
    __syncthreads();

    const int lane = t & 63, w = t >> 6;
    const int h = lane >> 5, ql = lane & 31;
    const int taskid = w >> 1, half = w & 1;
    const int qt = taskid ? (63 - qg) : qg;
    const int qbase = qt * 32;
    const int q = qbase + ql;
    const size_t baseQK = (size_t)bh * S_ * D_;

    // Q fragment: B[k=d][col=q], lane holds Q[q=ql][dc*16 + h*8 + j]
    bf16x8 qf[4];
#pragma unroll
    for (int dc = 0; dc < 4; ++dc)
        qf[dc] = *reinterpret_cast<const bf16x8*>(
            qb + baseQK + (size_t)q * D_ + dc * 16 + h * 8);

    f32x16 oa0, oa1;            // O^T partial: col=q, row=d within 32-d block
#pragma unroll
    for (int r = 0; r < 16; ++r) { oa0[r] = 0.f; oa1[r] = 0.f; }
    float mr = -3.0e38f, lr = 0.f;

    int kmax = qbase + 32; if (kmax < IMG_) kmax = IMG_;
    const int nt = (kmax + 31) >> 5;

    for (int kt = half; kt < nt; kt += 2) {
        const int k0 = kt * 32;
        // K fragment: A[row=key][k=d]
        bf16x8 kf[4];
#pragma unroll
        for (int dc = 0; dc < 4; ++dc)
            kf[dc] = *reinterpret_cast<const bf16x8*>(
                kb + baseQK + (size_t)(k0 + ql) * D_ + dc * 16 + h * 8);

        f32x16 s;
#pragma unroll
        for (int r = 0; r < 16; ++r) s[r] = 0.f;
#pragma unroll
        for (int dc = 0; dc < 4; ++dc)
            s = __builtin_amdgcn_mfma_f32_32x32x16_bf16(kf[dc], qf[dc], s, 0, 0, 0);
        // s[r] = score for key = k0 + (r&3) + 8*(r>>2) + 4*h, query = q

        float pna[16];
        *reinterpret_cast<float4*>(&pna[0])  = *reinterpret_cast<const float4*>(&pneg[k0 + 0  + 4 * h]);
        *reinterpret_cast<float4*>(&pna[4])  = *reinterpret_cast<const float4*>(&pneg[k0 + 8  + 4 * h]);
        *reinterpret_cast<float4*>(&pna[8])  = *reinterpret_cast<const float4*>(&pneg[k0 + 16 + 4 * h]);
        *reinterpret_cast<float4*>(&pna[12]) = *reinterpret_cast<const float4*>(&pneg[k0 + 24 + 4 * h]);
#pragma unroll
        for (int r = 0; r < 16; ++r) s[r] = fmaf(s[r], 0.125f, pna[r]);

        if (kt == nt - 1) {   // causal needed only on the terminal tile
#pragma unroll
            for (int r = 0; r < 16; ++r) {
                int key = k0 + (r & 3) + 8 * (r >> 2) + 4 * h;
                if (!((key <= q) || (key < IMG_))) s[r] = NEG_;
            }
        }

        // row max: 15 in-reg max + 1 cross-half swap
        float t0 = fmaxf(fmaxf(s[0], s[1]), fmaxf(s[2], s[3]));
        float t1 = fmaxf(fmaxf(s[4], s[5]), fmaxf(s[6], s[7]));
        float t2 = fmaxf(fmaxf(s[8], s[9]), fmaxf(s[10], s[11]));
        float t3 = fmaxf(fmaxf(s[12], s[13]), fmaxf(s[14], s[15]));
        float tm = fmaxf(fmaxf(t0, t1), fmaxf(t2, t3));
        tm = fmaxf(tm, __shfl_xor(tm, 32, 64));

        // defer-max (T13, THR=8)
        if (!__all(tm - mr <= 8.f)) {
            float mnew = fmaxf(mr, tm);
            float alpha = __expf(mr - mnew);
            mr = mnew; lr *= alpha;
#pragma unroll
            for (int r = 0; r < 16; ++r) { oa0[r] *= alpha; oa1[r] *= alpha; }
        }

        float p[16];
#pragma unroll
        for (int r = 0; r < 16; ++r) p[r] = __expf(s[r] - mr);
        float a0 = (p[0] + p[1]) + (p[2] + p[3]);
        float a1 = (p[4] + p[5]) + (p[6] + p[7]);
        float a2 = (p[8] + p[9]) + (p[10] + p[11]);
        float a3 = (p[12] + p[13]) + (p[14] + p[15]);
        float ss = (a0 + a1) + (a2 + a3);
        ss += __shfl_xor(ss, 32, 64);
        lr += ss;

        unsigned int pka0 = pack2(p[0], p[1]),   pkb0 = pack2(p[2], p[3]);
        unsigned int pka1 = pack2(p[4], p[5]),   pkb1 = pack2(p[6], p[7]);
        unsigned int pka2 = pack2(p[8], p[9]),   pkb2 = pack2(p[10], p[11]);
        unsigned int pka3 = pack2(p[12], p[13]), pkb3 = pack2(p[14], p[15]);

#pragma unroll
        for (int m = 0; m < 2; ++m) {
            unsigned int keep0 = h ? (m ? pka3 : pka1) : (m ? pka2 : pka0);
            unsigned int keep1 = h ? (m ? pkb3 : pkb1) : (m ? pkb2 : pkb0);
            unsigned int send0 = h ? (m ? pka2 : pka0) : (m ? pka3 : pka1);
            unsigned int send1 = h ? (m ? pkb2 : pkb0) : (m ? pkb3 : pkb1);
            unsigned int x0 = (unsigned int)__shfl_xor((int)send0, 32, 64);
            unsigned int x1 = (unsigned int)__shfl_xor((int)send1, 32, 64);
            uint4 fr;
            fr.x = h ? x0 : keep0;
            fr.y = h ? x1 : keep1;
            fr.z = h ? keep0 : x0;
            fr.w = h ? keep1 : x1;
            bf16x8 pb = __builtin_bit_cast(bf16x8, fr);
            bf16x8 vf0 = *reinterpret_cast<const bf16x8*>(
                vtb + ((size_t)bh * D_ + ql) * S_ + k0 + m * 16 + h * 8);
            bf16x8 vf1 = *reinterpret_cast<const bf16x8*>(
                vtb + ((size_t)bh * D_ + 32 + ql) * S_ + k0 + m * 16 + h * 8);
            oa0 = __builtin_amdgcn_mfma_f32_32x32x16_bf16(vf0, pb, oa0, 0, 0, 0);
            oa1 = __builtin_amdgcn_mfma_f32_32x32x16_bf16(vf1, pb, oa1, 0, 0, 0);
        }
    }

    // -------- pairwise merge of the two key-halves via LDS
    float* X = &exch[taskid][0][0];
    if (half) {
#pragma unroll
        for (int r = 0; r < 16; ++r) {
            X[r * 64 + lane] = oa0[r];
            X[(16 + r) * 64 + lane] = oa1[r];
        }
        X[32 * 64 + lane] = mr;
        X[33 * 64 + lane] = lr;
    }
    __syncthreads();
    if (half) return;

    float m1 = X[32 * 64 + lane], l1 = X[33 * 64 + lane];
    float mnew = fmaxf(mr, m1);
    float w0 = __expf(mr - mnew), w1 = __expf(m1 - mnew);
    float inv = 1.f / (lr * w0 + l1 * w1);

    unsigned short* orow = ob + ((size_t)(b * S_ + q)) * E_ + hh * D_;
#pragma unroll
    for (int gg = 0; gg < 4; ++gg) {
        int d0 = gg * 8 + 4 * h;
        float v0[4], v1[4];
#pragma unroll
        for (int j = 0; j < 4; ++j) {
            int r = 4 * gg + j;
            v0[j] = (oa0[r] * w0 + X[r * 64 + lane] * w1) * inv;
            v1[j] = (oa1[r] * w0 + X[(16 + r) * 64 + lane] * w1) * inv;
        }
        uint2 s0, s1;
        s0.x = pack2(v0[0], v0[1]); s0.y = pack2(v0[2], v0[3]);
        s1.x = pack2(v1[0], v1[1]); s1.y = pack2(v1[2], v1[3]);
        *reinterpret_cast<uint2*>(orow + d0) = s0;
        *reinterpret_cast<uint2*>(orow + 32 + d0) = s1;
    }
}

// ---------------------------------------------------------------- output projection
__global__ __launch_bounds__(256) void oproj_gemm(
    const unsigned short* __restrict__ ab,
    const unsigned short* __restrict__ wob,
    const float* __restrict__ bo,
    float* __restrict__ out)
{
    __shared__ __align__(16) unsigned short As[128 * 64];
    __shared__ __align__(16) unsigned short Bs[128 * 64];
    const int m0 = blockIdx.x * 128;
    const int n0 = blockIdx.y * 128;
    const int t = threadIdx.x;
    const int lane = t & 63, wid = t >> 6;
    const int wr = wid >> 1, wc = wid & 1;
    const int c = lane & 15, g = lane >> 4;
    const int srow = lane >> 3;
    const int sslot = (lane & 7) ^ srow;

    f32x4 acc[4][4];
#pragma unroll
    for (int i = 0; i < 4; ++i)
#pragma unroll
        for (int j = 0; j < 4; ++j) acc[i][j] = (f32x4){0.f, 0.f, 0.f, 0.f};

    for (int k0 = 0; k0 < E_; k0 += 64) {
        __syncthreads();
#pragma unroll
        for (int j = 0; j < 8; ++j) {
            int chunk = wid * 8 + j;
            int isB = chunk >> 4;
            int ch = chunk & 15;
            int row = ch * 8 + srow;
            const unsigned short* src =
                (isB ? wob + (size_t)(n0 + row) * E_
                     : ab + (size_t)(m0 + row) * E_) + k0 + sslot * 8;
            unsigned short* dst = (isB ? Bs : As) + ch * 512;
            gload16(src, dst);
        }
        __syncthreads();

        bf16x8 af[2][4], bfv[2][4];
#pragma unroll
        for (int kk = 0; kk < 2; ++kk) {
#pragma unroll
            for (int fr = 0; fr < 4; ++fr) {
                int row = wr * 64 + fr * 16 + c;
                af[kk][fr] = *reinterpret_cast<const bf16x8*>(
                    &As[row * 64 + (((kk * 4 + g) ^ (row & 7)) * 8)]);
            }
#pragma unroll
            for (int fc = 0; fc < 4; ++fc) {
                int row = wc * 64 + fc * 16 + c;
                bfv[kk][fc] = *reinterpret_cast<const bf16x8*>(
                    &Bs[row * 64 + (((kk * 4 + g) ^ (row & 7)) * 8)]);
            }
        }
#pragma unroll
        for (int kk = 0; kk < 2; ++kk)
#pragma unroll
            for (int fr = 0; fr < 4; ++fr)
#pragma unroll
                for (int fc = 0; fc < 4; ++fc)
                    acc[fr][fc] = __builtin_amdgcn_mfma_f32_16x16x32_bf16(
                        af[kk][fr], bfv[kk][fc], acc[fr][fc], 0, 0, 0);
    }

#pragma unroll
    for (int fc = 0; fc < 4; ++fc) {
        int n = n0 + wc * 64 + fc * 16 + c;
        float bias = bo[n];
#pragma unroll
        for (int fr = 0; fr < 4; ++fr)
#pragma unroll
            for (int r = 0; r < 4; ++r) {
                int m = m0 + wr * 64 + fr * 16 + g * 4 + r;
                out[(size_t)m * E_ + n] = acc[fr][fc][r] + bias;
            }
    }
}

// ---------------------------------------------------------------- launch
extern "C" void kernel_launch(void* const* d_in, const int* in_sizes, int n_in,
                              void* d_out, int out_size, void* d_ws, size_t ws_size,
                              hipStream_t stream) {
    const float* x  = (const float*)d_in[0];
    const int* pad  = (const int*)d_in[1];
    const float* Wq = (const float*)d_in[2];
    const float* bq = (const float*)d_in[3];
    const float* Wk = (const float*)d_in[4];
    const float* bk = (const float*)d_in[5];
    const float* Wv = (const float*)d_in[6];
    const float* bv = (const float*)d_in[7];
    const float* Wo = (const float*)d_in[8];
    const float* bo = (const float*)d_in[9];
    float* out = (float*)d_out;

    const size_t NX = (size_t)B_ * S_ * E_;   // 6291456
    const size_t NW = (size_t)E_ * E_;        // 589824
    unsigned short* ws = (unsigned short*)d_ws;
    unsigned short* xb  = ws;
    unsigned short* wqb = xb + NX;
    unsigned short* wkb = wqb + NW;
    unsigned short* wvb = wkb + NW;
    unsigned short* wob = wvb + NW;
    unsigned short* qb  = wob + NW;
    unsigned short* kb  = qb + NX;
    unsigned short* vtb = kb + NX;
    unsigned short* obuf = vtb + NX;
    float* padneg = (float*)(obuf + NX);      // B*S floats

    cvt_kernel<<<(int)(NX / 4 / 256), 256, 0, stream>>>(x, xb, (int)(NX / 4));
    cvt_kernel<<<(int)(NW / 4 / 256), 256, 0, stream>>>(Wq, wqb, (int)(NW / 4));
    cvt_kernel<<<(int)(NW / 4 / 256), 256, 0, stream>>>(Wk, wkb, (int)(NW / 4));
    cvt_kernel<<<(int)(NW / 4 / 256), 256, 0, stream>>>(Wv, wvb, (int)(NW / 4));
    cvt_kernel<<<(int)(NW / 4 / 256), 256, 0, stream>>>(Wo, wob, (int)(NW / 4));
    padneg_kernel<<<(B_ * S_) / 256, 256, 0, stream>>>(pad, padneg);

    qkv_gemm<<<dim3(64, 18), 256, 0, stream>>>(xb, wqb, wkb, wvb, bq, bk, bv,
                                               qb, kb, vtb);
    attn_kernel<<<dim3(1536), 256, 0, stream>>>(qb, kb, vtb, padneg, obuf);
    oproj_gemm<<<dim3(64, 6), 256, 0, stream>>>(obuf, wob, bo, out);
}

// Round 5
// 169.118 us; speedup vs baseline: 2.8601x; 1.1904x over previous
//
#include <hip/hip_runtime.h>

#define B_ 4
#define S_ 2048
#define E_ 768
#define H_ 12
#define D_ 64
#define IMG_ 196
#define TXT_ 1852
#define NEG_ (-1e9f)

typedef __bf16 bf16x8 __attribute__((ext_vector_type(8)));
typedef float f32x4 __attribute__((ext_vector_type(4)));
typedef float f32x16 __attribute__((ext_vector_type(16)));

__device__ __forceinline__ unsigned short f2b(float f) {
    __bf16 h = (__bf16)f;
    return __builtin_bit_cast(unsigned short, h);
}
__device__ __forceinline__ unsigned int pack2(float lo, float hi) {
    return (unsigned int)f2b(lo) | ((unsigned int)f2b(hi) << 16);
}
// async global->LDS, 16B per lane; LDS dest wave-uniform base + lane*16
__device__ __forceinline__ void gload16(const unsigned short* g, unsigned short* l) {
    __builtin_amdgcn_global_load_lds(
        (const __attribute__((address_space(1))) unsigned int*)g,
        (__attribute__((address_space(3))) unsigned int*)l, 16, 0, 0);
}

// Fragment-major layouts (bf16 elems):
//  QF/KF: [bh][t32][dc(4)][lane(64)][8]  elem = X[t32*32 + (lane&31)][dc*16 + (lane>>5)*8 + e8]
//  VF:    [bh][t32][m(2)][vh(2)][lane(64)][8]
//         elem = V[t32*32 + m*16 + (lane>>5)*8 + e8][vh*32 + (lane&31)]

// ---------------------------------------------------------------- conversion
__global__ __launch_bounds__(256) void cvt_kernel(const float* __restrict__ src,
                                                  unsigned short* __restrict__ dst,
                                                  int n4) {
    int i = blockIdx.x * 256 + threadIdx.x;
    if (i < n4) {
        float4 f = reinterpret_cast<const float4*>(src)[i];
        ushort4 u;
        u.x = f2b(f.x); u.y = f2b(f.y); u.z = f2b(f.z); u.w = f2b(f.w);
        reinterpret_cast<ushort4*>(dst)[i] = u;
    }
}

// padneg[b][s] = 0 if key s is pad-valid, -1e9 if padded out
__global__ __launch_bounds__(256) void padneg_kernel(const int* __restrict__ pad,
                                                     float* __restrict__ padneg) {
    int i = blockIdx.x * 256 + threadIdx.x;      // over B*S
    if (i < B_ * S_) {
        int b = i >> 11, s = i & 2047;
        float v = 0.f;
        if (s >= IMG_) v = pad[b * TXT_ + (s - IMG_)] ? 0.f : NEG_;
        padneg[i] = v;
    }
}

// ---------------------------------------------------------------- QKV GEMM
// 128x128 tile, BK=64, global_load_lds staging; epilogue writes fragment-major.
__global__ __launch_bounds__(256) void qkv_gemm(
    const unsigned short* __restrict__ xb,
    const unsigned short* __restrict__ wqb,
    const unsigned short* __restrict__ wkb,
    const unsigned short* __restrict__ wvb,
    const float* __restrict__ bq, const float* __restrict__ bk,
    const float* __restrict__ bv,
    unsigned short* __restrict__ qfb, unsigned short* __restrict__ kfb,
    unsigned short* __restrict__ vfb)
{
    __shared__ __align__(16) unsigned short As[128 * 64];
    __shared__ __align__(16) unsigned short Bs[128 * 64];
    const int m0 = blockIdx.x * 128;
    const int n0 = blockIdx.y * 128;
    const int which = n0 / E_;
    const int ncol0 = n0 % E_;
    const unsigned short* W = (which == 0) ? wqb : ((which == 1) ? wkb : wvb);
    const int t = threadIdx.x;
    const int lane = t & 63, wid = t >> 6;
    const int wr = wid >> 1, wc = wid & 1;
    const int c = lane & 15, g = lane >> 4;
    const int srow = lane >> 3;            // row within 8-row chunk
    const int sslot = (lane & 7) ^ srow;   // pre-swizzled source 16B-slot

    f32x4 acc[4][4];
#pragma unroll
    for (int i = 0; i < 4; ++i)
#pragma unroll
        for (int j = 0; j < 4; ++j) acc[i][j] = (f32x4){0.f, 0.f, 0.f, 0.f};

    for (int k0 = 0; k0 < E_; k0 += 64) {
        __syncthreads();   // prev-iter LDS reads done
#pragma unroll
        for (int j = 0; j < 8; ++j) {
            int chunk = wid * 8 + j;       // 0..31 (wave-uniform)
            int isB = chunk >> 4;
            int ch = chunk & 15;
            int row = ch * 8 + srow;
            const unsigned short* src =
                (isB ? W + (size_t)(ncol0 + row) * E_
                     : xb + (size_t)(m0 + row) * E_) + k0 + sslot * 8;
            unsigned short* dst = (isB ? Bs : As) + ch * 512;
            gload16(src, dst);
        }
        __syncthreads();   // staging visible (vmcnt drained by barrier)

        bf16x8 af[2][4], bfv[2][4];
#pragma unroll
        for (int kk = 0; kk < 2; ++kk) {
#pragma unroll
            for (int fr = 0; fr < 4; ++fr) {
                int row = wr * 64 + fr * 16 + c;
                af[kk][fr] = *reinterpret_cast<const bf16x8*>(
                    &As[row * 64 + (((kk * 4 + g) ^ (row & 7)) * 8)]);
            }
#pragma unroll
            for (int fc = 0; fc < 4; ++fc) {
                int row = wc * 64 + fc * 16 + c;
                bfv[kk][fc] = *reinterpret_cast<const bf16x8*>(
                    &Bs[row * 64 + (((kk * 4 + g) ^ (row & 7)) * 8)]);
            }
        }
#pragma unroll
        for (int kk = 0; kk < 2; ++kk)
#pragma unroll
            for (int fr = 0; fr < 4; ++fr)
#pragma unroll
                for (int fc = 0; fc < 4; ++fc)
                    acc[fr][fc] = __builtin_amdgcn_mfma_f32_16x16x32_bf16(
                        af[kk][fr], bfv[kk][fc], acc[fr][fc], 0, 0, 0);
    }

    const float* bias_ptr = (which == 0) ? bq : ((which == 1) ? bk : bv);
    if (which != 2) {
        unsigned short* dstbuf = (which == 0) ? qfb : kfb;
#pragma unroll
        for (int fc = 0; fc < 4; ++fc) {
            int e = ncol0 + wc * 64 + fc * 16 + c;
            float bias = bias_ptr[e];
            int hd = e >> 6, d = e & 63;
            int dc = d >> 4, hf = (d >> 3) & 1, e8 = d & 7;
#pragma unroll
            for (int fr = 0; fr < 4; ++fr) {
#pragma unroll
                for (int r = 0; r < 4; ++r) {
                    int m = m0 + wr * 64 + fr * 16 + g * 4 + r;
                    int b = m >> 11, s = m & 2047;
                    int bh = b * H_ + hd, t32 = s >> 5, sl = s & 31;
                    size_t off = ((((size_t)bh * 64 + t32) * 4 + dc) * 64
                                  + hf * 32 + sl) * 8 + e8;
                    dstbuf[off] = f2b(acc[fr][fc][r] + bias);
                }
            }
        }
    } else {
#pragma unroll
        for (int fc = 0; fc < 4; ++fc) {
            int e = ncol0 + wc * 64 + fc * 16 + c;
            float bias = bias_ptr[e];
            int hd = e >> 6, d = e & 63;
            int vh = d >> 5, dl = d & 31;
#pragma unroll
            for (int fr = 0; fr < 4; ++fr) {
                int m = m0 + wr * 64 + fr * 16 + g * 4;   // r = 0 token
                int b = m >> 11, s = m & 2047;
                int bh = b * H_ + hd, t32 = s >> 5, ks = s & 31;
                int mm = ks >> 4, hb = (ks >> 3) & 1, e8 = ks & 7;  // e8 in {0,4}
                size_t off = (((((size_t)bh * 64 + t32) * 2 + mm) * 2 + vh) * 64
                              + hb * 32 + dl) * 8 + e8;
                uint2 pk;
                pk.x = pack2(acc[fr][fc][0] + bias, acc[fr][fc][1] + bias);
                pk.y = pack2(acc[fr][fc][2] + bias, acc[fr][fc][3] + bias);
                *reinterpret_cast<uint2*>(&vfb[off]) = pk;   // 8B-aligned packed store
            }
        }
    }
}

// ---------------------------------------------------------------- flash attention
// Split-K: each (bh, 32-query tile) handled by TWO waves (key tiles by parity),
// merged via LDS. Swapped QK^T (32x32x16): C col = query; softmax lane-local.
// All Q/K/V fragment loads are coalesced (fragment-major layout).
__global__ __launch_bounds__(256) void attn_kernel(
    const unsigned short* __restrict__ qfb,
    const unsigned short* __restrict__ kfb,
    const unsigned short* __restrict__ vfb,
    const float* __restrict__ padneg,
    unsigned short* __restrict__ ob)
{
    __shared__ float pneg[S_];
    __shared__ float exch[2][34][64];
    const int flat = blockIdx.x;                 // 0..1535
    const int xcd = flat & 7, idx = flat >> 3;   // XCD-locality remap (T1)
    const int bh = xcd * 6 + (idx >> 5);         // one head stays on one XCD
    const int qg = idx & 31;
    const int b = bh / H_, hh = bh % H_;
    const int t = threadIdx.x;

    {   // pad mask -> LDS
        const float4* src = reinterpret_cast<const float4*>(padneg + b * S_);
        float4* dst = reinterpret_cast<float4*>(pneg);
        dst[t] = src[t];
        dst[t + 256] = src[t + 256];
    }
    __syncthreads();

    const int lane = t & 63, w = t >> 6;
    const int h = lane >> 5, ql = lane & 31;
    const int taskid = w >> 1, half = w & 1;
    const int qt = taskid ? (63 - qg) : qg;
    const int qbase = qt * 32;
    const int q = qbase + ql;

    // Q fragment: coalesced from fragment-major buffer
    bf16x8 qf[4];
    {
        const unsigned short* qp = qfb + ((size_t)(bh * 64 + qt) * 4) * 512 + lane * 8;
#pragma unroll
        for (int dc = 0; dc < 4; ++dc)
            qf[dc] = *reinterpret_cast<const bf16x8*>(qp + dc * 512);
    }

    f32x16 oa0, oa1;            // O^T partial: col=q, row=d within 32-d block
#pragma unroll
    for (int r = 0; r < 16; ++r) { oa0[r] = 0.f; oa1[r] = 0.f; }
    float mr = -3.0e38f, lr = 0.f;

    int kmax = qbase + 32; if (kmax < IMG_) kmax = IMG_;
    const int nt = (kmax + 31) >> 5;

    for (int kt = half; kt < nt; kt += 2) {
        const int k0 = kt * 32;
        // K fragment: coalesced
        bf16x8 kf[4];
        {
            const unsigned short* kp = kfb + ((size_t)(bh * 64 + kt) * 4) * 512 + lane * 8;
#pragma unroll
            for (int dc = 0; dc < 4; ++dc)
                kf[dc] = *reinterpret_cast<const bf16x8*>(kp + dc * 512);
        }

        f32x16 s;
#pragma unroll
        for (int r = 0; r < 16; ++r) s[r] = 0.f;
#pragma unroll
        for (int dc = 0; dc < 4; ++dc)
            s = __builtin_amdgcn_mfma_f32_32x32x16_bf16(kf[dc], qf[dc], s, 0, 0, 0);
        // s[r] = score for key = k0 + (r&3) + 8*(r>>2) + 4*h, query = q

        float pna[16];
        *reinterpret_cast<float4*>(&pna[0])  = *reinterpret_cast<const float4*>(&pneg[k0 + 0  + 4 * h]);
        *reinterpret_cast<float4*>(&pna[4])  = *reinterpret_cast<const float4*>(&pneg[k0 + 8  + 4 * h]);
        *reinterpret_cast<float4*>(&pna[8])  = *reinterpret_cast<const float4*>(&pneg[k0 + 16 + 4 * h]);
        *reinterpret_cast<float4*>(&pna[12]) = *reinterpret_cast<const float4*>(&pneg[k0 + 24 + 4 * h]);
#pragma unroll
        for (int r = 0; r < 16; ++r) s[r] = fmaf(s[r], 0.125f, pna[r]);

        if (kt == nt - 1) {   // causal needed only on the terminal tile
#pragma unroll
            for (int r = 0; r < 16; ++r) {
                int key = k0 + (r & 3) + 8 * (r >> 2) + 4 * h;
                if (!((key <= q) || (key < IMG_))) s[r] = NEG_;
            }
        }

        // row max: 15 in-reg max + 1 cross-half swap
        float t0 = fmaxf(fmaxf(s[0], s[1]), fmaxf(s[2], s[3]));
        float t1 = fmaxf(fmaxf(s[4], s[5]), fmaxf(s[6], s[7]));
        float t2 = fmaxf(fmaxf(s[8], s[9]), fmaxf(s[10], s[11]));
        float t3 = fmaxf(fmaxf(s[12], s[13]), fmaxf(s[14], s[15]));
        float tm = fmaxf(fmaxf(t0, t1), fmaxf(t2, t3));
        tm = fmaxf(tm, __shfl_xor(tm, 32, 64));

        // defer-max (T13, THR=8)
        if (!__all(tm - mr <= 8.f)) {
            float mnew = fmaxf(mr, tm);
            float alpha = __expf(mr - mnew);
            mr = mnew; lr *= alpha;
#pragma unroll
            for (int r = 0; r < 16; ++r) { oa0[r] *= alpha; oa1[r] *= alpha; }
        }

        float p[16];
#pragma unroll
        for (int r = 0; r < 16; ++r) p[r] = __expf(s[r] - mr);
        float a0 = (p[0] + p[1]) + (p[2] + p[3]);
        float a1 = (p[4] + p[5]) + (p[6] + p[7]);
        float a2 = (p[8] + p[9]) + (p[10] + p[11]);
        float a3 = (p[12] + p[13]) + (p[14] + p[15]);
        float ss = (a0 + a1) + (a2 + a3);
        ss += __shfl_xor(ss, 32, 64);
        lr += ss;

        unsigned int pka0 = pack2(p[0], p[1]),   pkb0 = pack2(p[2], p[3]);
        unsigned int pka1 = pack2(p[4], p[5]),   pkb1 = pack2(p[6], p[7]);
        unsigned int pka2 = pack2(p[8], p[9]),   pkb2 = pack2(p[10], p[11]);
        unsigned int pka3 = pack2(p[12], p[13]), pkb3 = pack2(p[14], p[15]);

        const unsigned short* vp = vfb + ((size_t)(bh * 64 + kt) * 4) * 512 + lane * 8;
#pragma unroll
        for (int m = 0; m < 2; ++m) {
            unsigned int keep0 = h ? (m ? pka3 : pka1) : (m ? pka2 : pka0);
            unsigned int keep1 = h ? (m ? pkb3 : pkb1) : (m ? pkb2 : pkb0);
            unsigned int send0 = h ? (m ? pka2 : pka0) : (m ? pka3 : pka1);
            unsigned int send1 = h ? (m ? pkb2 : pkb0) : (m ? pkb3 : pkb1);
            unsigned int x0 = (unsigned int)__shfl_xor((int)send0, 32, 64);
            unsigned int x1 = (unsigned int)__shfl_xor((int)send1, 32, 64);
            uint4 fr;
            fr.x = h ? x0 : keep0;
            fr.y = h ? x1 : keep1;
            fr.z = h ? keep0 : x0;
            fr.w = h ? keep1 : x1;
            bf16x8 pb = __builtin_bit_cast(bf16x8, fr);
            bf16x8 vf0 = *reinterpret_cast<const bf16x8*>(vp + (m * 2 + 0) * 512);
            bf16x8 vf1 = *reinterpret_cast<const bf16x8*>(vp + (m * 2 + 1) * 512);
            oa0 = __builtin_amdgcn_mfma_f32_32x32x16_bf16(vf0, pb, oa0, 0, 0, 0);
            oa1 = __builtin_amdgcn_mfma_f32_32x32x16_bf16(vf1, pb, oa1, 0, 0, 0);
        }
    }

    // -------- pairwise merge of the two key-halves via LDS
    float* X = &exch[taskid][0][0];
    if (half) {
#pragma unroll
        for (int r = 0; r < 16; ++r) {
            X[r * 64 + lane] = oa0[r];
            X[(16 + r) * 64 + lane] = oa1[r];
        }
        X[32 * 64 + lane] = mr;
        X[33 * 64 + lane] = lr;
    }
    __syncthreads();
    if (half) return;

    float m1 = X[32 * 64 + lane], l1 = X[33 * 64 + lane];
    float mnew = fmaxf(mr, m1);
    float w0 = __expf(mr - mnew), w1 = __expf(m1 - mnew);
    float inv = 1.f / (lr * w0 + l1 * w1);

    unsigned short* orow = ob + ((size_t)(b * S_ + q)) * E_ + hh * D_;
#pragma unroll
    for (int gg = 0; gg < 4; ++gg) {
        int d0 = gg * 8 + 4 * h;
        float v0[4], v1[4];
#pragma unroll
        for (int j = 0; j < 4; ++j) {
            int r = 4 * gg + j;
            v0[j] = (oa0[r] * w0 + X[r * 64 + lane] * w1) * inv;
            v1[j] = (oa1[r] * w0 + X[(16 + r) * 64 + lane] * w1) * inv;
        }
        uint2 s0, s1;
        s0.x = pack2(v0[0], v0[1]); s0.y = pack2(v0[2], v0[3]);
        s1.x = pack2(v1[0], v1[1]); s1.y = pack2(v1[2], v1[3]);
        *reinterpret_cast<uint2*>(orow + d0) = s0;
        *reinterpret_cast<uint2*>(orow + 32 + d0) = s1;
    }
}

// ---------------------------------------------------------------- output projection
__global__ __launch_bounds__(256) void oproj_gemm(
    const unsigned short* __restrict__ ab,
    const unsigned short* __restrict__ wob,
    const float* __restrict__ bo,
    float* __restrict__ out)
{
    __shared__ __align__(16) unsigned short As[128 * 64];
    __shared__ __align__(16) unsigned short Bs[128 * 64];
    const int m0 = blockIdx.x * 128;
    const int n0 = blockIdx.y * 128;
    const int t = threadIdx.x;
    const int lane = t & 63, wid = t >> 6;
    const int wr = wid >> 1, wc = wid & 1;
    const int c = lane & 15, g = lane >> 4;
    const int srow = lane >> 3;
    const int sslot = (lane & 7) ^ srow;

    f32x4 acc[4][4];
#pragma unroll
    for (int i = 0; i < 4; ++i)
#pragma unroll
        for (int j = 0; j < 4; ++j) acc[i][j] = (f32x4){0.f, 0.f, 0.f, 0.f};

    for (int k0 = 0; k0 < E_; k0 += 64) {
        __syncthreads();
#pragma unroll
        for (int j = 0; j < 8; ++j) {
            int chunk = wid * 8 + j;
            int isB = chunk >> 4;
            int ch = chunk & 15;
            int row = ch * 8 + srow;
            const unsigned short* src =
                (isB ? wob + (size_t)(n0 + row) * E_
                     : ab + (size_t)(m0 + row) * E_) + k0 + sslot * 8;
            unsigned short* dst = (isB ? Bs : As) + ch * 512;
            gload16(src, dst);
        }
        __syncthreads();

        bf16x8 af[2][4], bfv[2][4];
#pragma unroll
        for (int kk = 0; kk < 2; ++kk) {
#pragma unroll
            for (int fr = 0; fr < 4; ++fr) {
                int row = wr * 64 + fr * 16 + c;
                af[kk][fr] = *reinterpret_cast<const bf16x8*>(
                    &As[row * 64 + (((kk * 4 + g) ^ (row & 7)) * 8)]);
            }
#pragma unroll
            for (int fc = 0; fc < 4; ++fc) {
                int row = wc * 64 + fc * 16 + c;
                bfv[kk][fc] = *reinterpret_cast<const bf16x8*>(
                    &Bs[row * 64 + (((kk * 4 + g) ^ (row & 7)) * 8)]);
            }
        }
#pragma unroll
        for (int kk = 0; kk < 2; ++kk)
#pragma unroll
            for (int fr = 0; fr < 4; ++fr)
#pragma unroll
                for (int fc = 0; fc < 4; ++fc)
                    acc[fr][fc] = __builtin_amdgcn_mfma_f32_16x16x32_bf16(
                        af[kk][fr], bfv[kk][fc], acc[fr][fc], 0, 0, 0);
    }

#pragma unroll
    for (int fc = 0; fc < 4; ++fc) {
        int n = n0 + wc * 64 + fc * 16 + c;
        float bias = bo[n];
#pragma unroll
        for (int fr = 0; fr < 4; ++fr)
#pragma unroll
            for (int r = 0; r < 4; ++r) {
                int m = m0 + wr * 64 + fr * 16 + g * 4 + r;
                out[(size_t)m * E_ + n] = acc[fr][fc][r] + bias;
            }
    }
}

// ---------------------------------------------------------------- launch
extern "C" void kernel_launch(void* const* d_in, const int* in_sizes, int n_in,
                              void* d_out, int out_size, void* d_ws, size_t ws_size,
                              hipStream_t stream) {
    const float* x  = (const float*)d_in[0];
    const int* pad  = (const int*)d_in[1];
    const float* Wq = (const float*)d_in[2];
    const float* bq = (const float*)d_in[3];
    const float* Wk = (const float*)d_in[4];
    const float* bk = (const float*)d_in[5];
    const float* Wv = (const float*)d_in[6];
    const float* bv = (const float*)d_in[7];
    const float* Wo = (const float*)d_in[8];
    const float* bo = (const float*)d_in[9];
    float* out = (float*)d_out;

    const size_t NX = (size_t)B_ * S_ * E_;   // 6291456
    const size_t NW = (size_t)E_ * E_;        // 589824
    unsigned short* ws = (unsigned short*)d_ws;
    unsigned short* xb  = ws;
    unsigned short* wqb = xb + NX;
    unsigned short* wkb = wqb + NW;
    unsigned short* wvb = wkb + NW;
    unsigned short* wob = wvb + NW;
    unsigned short* qfb = wob + NW;
    unsigned short* kfb = qfb + NX;
    unsigned short* vfb = kfb + NX;
    unsigned short* obuf = vfb + NX;
    float* padneg = (float*)(obuf + NX);      // B*S floats

    cvt_kernel<<<(int)(NX / 4 / 256), 256, 0, stream>>>(x, xb, (int)(NX / 4));
    cvt_kernel<<<(int)(NW / 4 / 256), 256, 0, stream>>>(Wq, wqb, (int)(NW / 4));
    cvt_kernel<<<(int)(NW / 4 / 256), 256, 0, stream>>>(Wk, wkb, (int)(NW / 4));
    cvt_kernel<<<(int)(NW / 4 / 256), 256, 0, stream>>>(Wv, wvb, (int)(NW / 4));
    cvt_kernel<<<(int)(NW / 4 / 256), 256, 0, stream>>>(Wo, wob, (int)(NW / 4));
    padneg_kernel<<<(B_ * S_) / 256, 256, 0, stream>>>(pad, padneg);

    qkv_gemm<<<dim3(64, 18), 256, 0, stream>>>(xb, wqb, wkb, wvb, bq, bk, bv,
                                               qfb, kfb, vfb);
    attn_kernel<<<dim3(1536), 256, 0, stream>>>(qfb, kfb, vfb, padneg, obuf);
    oproj_gemm<<<dim3(64, 6), 256, 0, stream>>>(obuf, wob, bo, out);
}